// Round 1
// 328.319 us; speedup vs baseline: 1.0182x; 1.0182x over previous
//
#include <hip/hip_runtime.h>

// TT-matrix embedding: vocab 50*60*60, embed 8*8*8, rank 16.
//
// Three-phase scheme (round 2):
//   Phase 1: t12 tab[pair=i1*60+i2] = g1[i1] @ g2[i2]  (3000 x 1024 floats = 12.3 MB in d_ws)
//            layout: tab[pair*1024 + q*256 + ab*4 + j]  (s = 4q+j, ab = a*8+b) so a wave's
//            lane `ab` fetches its 16 s-values with 4 fully-coalesced float4 loads.
//   Phase 1b: counting sort of the 131072 tokens by pair id (hist -> scan -> scatter).
//            Rationale: 131072 tokens / 3000 pairs = 43.7x reuse of each 4 KB tab row.
//            The round-1 kernel re-read 4 KB per token (536 MB of L2/LLC traffic from a
//            12.3 MB table that misses the 4 MiB per-XCD L2 ~2/3 of the time). Sorting
//            lets each wave keep the tab row in registers across tokens of the same pair.
//   Phase 2: one wave per CHUNK=16 pair-sorted tokens. Reloads the 4 KB tab row only on
//            pair change (~1.37x per chunk). g3 (30 KB) stays scalar/L1-resident.
//            Per-token math identical to round 1 -> identical absmax.
//
// Predicted: embed phase goes from LLC-read-bound to write-bound (~268 MB out @ ~6 TB/s).

#define M2M3 3600u
#define M3   60u
#define NPAIR 3000
#define CHUNK 16

// ---------------- Phase 1: pair table ----------------
__global__ __launch_bounds__(256) void tt_pair_kernel(
    const float* __restrict__ c1,   // [50][8][16]
    const float* __restrict__ c2,   // [60][16][8][16]
    float* __restrict__ tab)        // [3000][1024]
{
    const int pair = blockIdx.x;            // i1*60 + i2
    const int i1 = pair / 60;
    const int i2 = pair - i1 * 60;
    const int tid = threadIdx.x;
    const int q  = tid >> 6;                // s-quad 0..3
    const int ab = tid & 63;
    const int a  = ab >> 3;
    const int b  = ab & 7;

    const float* __restrict__ g1 = c1 + i1 * 128 + a * 16;            // g1[a][r]
    const float* __restrict__ g2 = c2 + i2 * 2048 + b * 16 + q * 4;   // g2[r][b][4q..]

    float4 acc = make_float4(0.f, 0.f, 0.f, 0.f);
#pragma unroll
    for (int r = 0; r < 16; ++r) {
        const float a1 = g1[r];
        const float4 v = *(const float4*)(g2 + r * 128);
        acc.x = fmaf(a1, v.x, acc.x);
        acc.y = fmaf(a1, v.y, acc.y);
        acc.z = fmaf(a1, v.z, acc.z);
        acc.w = fmaf(a1, v.w, acc.w);
    }
    *(float4*)(tab + (size_t)pair * 1024 + tid * 4) = acc;
}

// ---------------- Phase 1b: counting sort by pair ----------------
__global__ __launch_bounds__(256) void tt_zero_counts(unsigned* __restrict__ counts)
{
    const int i = blockIdx.x * blockDim.x + threadIdx.x;
    if (i < NPAIR) counts[i] = 0u;
}

__global__ __launch_bounds__(256) void tt_hist(
    const int* __restrict__ x, unsigned* __restrict__ counts, int T)
{
    const int t = blockIdx.x * blockDim.x + threadIdx.x;
    if (t >= T) return;
    const unsigned id = (unsigned)x[t];
    atomicAdd(&counts[id / M3], 1u);        // pair = i1*60+i2 = id/60
}

// single-block exclusive scan of 3000 counts -> cursor (Hillis-Steele over 1024 partials)
__global__ __launch_bounds__(1024) void tt_scan(
    const unsigned* __restrict__ counts, unsigned* __restrict__ cursor)
{
    __shared__ unsigned buf[1024];
    const int tid = threadIdx.x;
    const int b = tid * 3;
    unsigned c0 = 0, c1 = 0, c2 = 0;
    if (b     < NPAIR) c0 = counts[b];
    if (b + 1 < NPAIR) c1 = counts[b + 1];
    if (b + 2 < NPAIR) c2 = counts[b + 2];
    const unsigned local = c0 + c1 + c2;
    buf[tid] = local;
    __syncthreads();
    for (int off = 1; off < 1024; off <<= 1) {
        const unsigned v = (tid >= off) ? buf[tid - off] : 0u;
        __syncthreads();
        buf[tid] += v;
        __syncthreads();
    }
    const unsigned excl = buf[tid] - local;
    if (b     < NPAIR) cursor[b]     = excl;
    if (b + 1 < NPAIR) cursor[b + 1] = excl + c0;
    if (b + 2 < NPAIR) cursor[b + 2] = excl + c0 + c1;
}

__global__ __launch_bounds__(256) void tt_scatter(
    const int* __restrict__ x, unsigned* __restrict__ cursor,
    unsigned* __restrict__ recT, unsigned* __restrict__ recPI, int T)
{
    const int t = blockIdx.x * blockDim.x + threadIdx.x;
    if (t >= T) return;
    const unsigned id   = (unsigned)x[t];
    const unsigned pair = id / M3;
    const unsigned i3   = id - pair * M3;
    const unsigned pos  = atomicAdd(&cursor[pair], 1u);
    recT[pos]  = (unsigned)t;               // original flat token index (output row)
    recPI[pos] = (pair << 6) | i3;          // pair:12b | i3:6b
}

// ---------------- Phase 2: sorted embed ----------------
__global__ __launch_bounds__(256) void tt_embed_sorted(
    const unsigned* __restrict__ recT,
    const unsigned* __restrict__ recPI,
    const float* __restrict__ c3,   // [60][16][8]
    const float* __restrict__ tab,  // [3000][1024]
    float* __restrict__ out,        // [T][512]
    int T)
{
    const int wid  = (int)((blockIdx.x * blockDim.x + threadIdx.x) >> 6);
    const int lane = threadIdx.x & 63;
    const int base = wid * CHUNK;
    if (base >= T) return;

    // lanes 0..CHUNK-1 stage this wave's records in registers (coalesced 64/128B loads)
    unsigned rT = 0u, rP = 0u;
    if (lane < CHUNK && base + lane < T) {
        rT = recT[base + lane];
        rP = recPI[base + lane];
    }

    const int n = min(CHUNK, T - base);     // wave-uniform
    float4 t4[4];
    int cur = -1;

    for (int j = 0; j < n; ++j) {
        // broadcast record j to scalar registers (runtime-uniform lane index)
        const unsigned tt = __builtin_amdgcn_readlane(rT, j);
        const unsigned pi = __builtin_amdgcn_readlane(rP, j);
        const int      pair = (int)(pi >> 6);
        const unsigned i3   = pi & 63u;

        if (pair != cur) {                  // wave-uniform branch: ~1.37x per chunk
            cur = pair;
            const float* tp = tab + (size_t)pair * 1024u;
#pragma unroll
            for (int q = 0; q < 4; ++q)
                t4[q] = *(const float4*)(tp + q * 256 + lane * 4);
        }
        const float* tf = (const float*)t4; // tf[s], s = 0..15

        const float4* __restrict__ g3 = (const float4*)(c3 + i3 * 128u); // scalar base

        float o[8];
#pragma unroll
        for (int c = 0; c < 8; ++c) o[c] = 0.f;
#pragma unroll
        for (int s = 0; s < 16; ++s) {
            const float ts = tf[s];
            const float4 w0 = g3[s * 2 + 0];
            const float4 w1 = g3[s * 2 + 1];
            o[0] = fmaf(ts, w0.x, o[0]);
            o[1] = fmaf(ts, w0.y, o[1]);
            o[2] = fmaf(ts, w0.z, o[2]);
            o[3] = fmaf(ts, w0.w, o[3]);
            o[4] = fmaf(ts, w1.x, o[4]);
            o[5] = fmaf(ts, w1.y, o[5]);
            o[6] = fmaf(ts, w1.z, o[6]);
            o[7] = fmaf(ts, w1.w, o[7]);
        }

        float4* dst = (float4*)(out + (size_t)tt * 512u + lane * 8);
        dst[0] = make_float4(o[0], o[1], o[2], o[3]);
        dst[1] = make_float4(o[4], o[5], o[6], o[7]);
    }
}

// ---------------- Fallback: round-1 two-phase (ws fits tab only) ----------------
__global__ __launch_bounds__(256) void tt_embed2_kernel(
    const int* __restrict__ x, const float* __restrict__ c3,
    const float* __restrict__ tab, float* __restrict__ out, int T)
{
    const int u    = (int)((blockIdx.x * blockDim.x + threadIdx.x) >> 6);
    const int lane = threadIdx.x & 63;
    if (u >= T) return;
    const unsigned id  = __builtin_amdgcn_readfirstlane((unsigned)x[u]);
    const unsigned i1  = id / M2M3;
    const unsigned rem = id - i1 * M2M3;
    const unsigned i2  = rem / M3;
    const unsigned i3  = rem - i2 * M3;
    const float* tp = tab + (size_t)(i1 * 60u + i2) * 1024u;
    float4 t[4];
#pragma unroll
    for (int q = 0; q < 4; ++q)
        t[q] = *(const float4*)(tp + q * 256 + lane * 4);
    const float* tf = (const float*)t;
    const float4* __restrict__ g3 = (const float4*)(c3 + i3 * 128u);
    float o[8];
#pragma unroll
    for (int c = 0; c < 8; ++c) o[c] = 0.f;
#pragma unroll
    for (int s = 0; s < 16; ++s) {
        const float ts = tf[s];
        const float4 w0 = g3[s * 2 + 0];
        const float4 w1 = g3[s * 2 + 1];
        o[0]=fmaf(ts,w0.x,o[0]); o[1]=fmaf(ts,w0.y,o[1]);
        o[2]=fmaf(ts,w0.z,o[2]); o[3]=fmaf(ts,w0.w,o[3]);
        o[4]=fmaf(ts,w1.x,o[4]); o[5]=fmaf(ts,w1.y,o[5]);
        o[6]=fmaf(ts,w1.z,o[6]); o[7]=fmaf(ts,w1.w,o[7]);
    }
    float4* dst = (float4*)(out + (size_t)u * 512 + lane * 8);
    dst[0] = make_float4(o[0], o[1], o[2], o[3]);
    dst[1] = make_float4(o[4], o[5], o[6], o[7]);
}

// ---------------- Fallback: round-1 single-pass (tiny ws) ----------------
__global__ __launch_bounds__(256) void tt_embed_kernel(
    const int* __restrict__ x, const float* __restrict__ c1,
    const float* __restrict__ c2, const float* __restrict__ c3,
    float* __restrict__ out, int T)
{
    const int u    = (int)((blockIdx.x * blockDim.x + threadIdx.x) >> 6);
    const int lane = threadIdx.x & 63;
    if (u >= T) return;
    const int a = lane >> 3, b = lane & 7;
    const unsigned id  = (unsigned)x[u];
    const unsigned i1  = id / M2M3;
    const unsigned rem = id - i1 * M2M3;
    const unsigned i2  = rem / M3;
    const unsigned i3  = rem - i2 * M3;
    const float4* g1 = (const float4*)(c1 + i1 * 128u + a * 16);
    const float*  g2 = c2 + i2 * 2048u + b * 16;
    const float4* g3 = (const float4*)(c3 + i3 * 128u);
    float4 a1v[4];
#pragma unroll
    for (int q = 0; q < 4; ++q) a1v[q] = g1[q];
    const float* a1f = (const float*)a1v;
    float t12[16];
#pragma unroll
    for (int s = 0; s < 16; ++s) t12[s] = 0.f;
#pragma unroll
    for (int r = 0; r < 16; ++r) {
        const float a1 = a1f[r];
        const float4* row = (const float4*)(g2 + r * 128);
#pragma unroll
        for (int q = 0; q < 4; ++q) {
            const float4 v = row[q];
            t12[q*4+0] = fmaf(a1, v.x, t12[q*4+0]);
            t12[q*4+1] = fmaf(a1, v.y, t12[q*4+1]);
            t12[q*4+2] = fmaf(a1, v.z, t12[q*4+2]);
            t12[q*4+3] = fmaf(a1, v.w, t12[q*4+3]);
        }
    }
    float o[8];
#pragma unroll
    for (int c = 0; c < 8; ++c) o[c] = 0.f;
#pragma unroll
    for (int s = 0; s < 16; ++s) {
        const float ts = t12[s];
        const float4 w0 = g3[s*2+0];
        const float4 w1 = g3[s*2+1];
        o[0]=fmaf(ts,w0.x,o[0]); o[1]=fmaf(ts,w0.y,o[1]);
        o[2]=fmaf(ts,w0.z,o[2]); o[3]=fmaf(ts,w0.w,o[3]);
        o[4]=fmaf(ts,w1.x,o[4]); o[5]=fmaf(ts,w1.y,o[5]);
        o[6]=fmaf(ts,w1.z,o[6]); o[7]=fmaf(ts,w1.w,o[7]);
    }
    float4* dst = (float4*)(out + (size_t)u * 512 + lane * 8);
    dst[0] = make_float4(o[0], o[1], o[2], o[3]);
    dst[1] = make_float4(o[4], o[5], o[6], o[7]);
}

extern "C" void kernel_launch(void* const* d_in, const int* in_sizes, int n_in,
                              void* d_out, int out_size, void* d_ws, size_t ws_size,
                              hipStream_t stream) {
    const int*   x  = (const int*)d_in[0];
    const float* c1 = (const float*)d_in[1];
    const float* c2 = (const float*)d_in[2];
    const float* c3 = (const float*)d_in[3];
    float* out = (float*)d_out;

    const int T = in_sizes[0];                        // 131072 tokens

    // workspace layout (all regions fully rewritten every launch; poison-safe)
    const size_t tab_bytes  = (size_t)NPAIR * 1024u * sizeof(float);   // 12,288,000
    const size_t off_counts = tab_bytes;                               // 3000 u32
    const size_t off_cursor = off_counts + 12032;                      // 3000 u32 (padded)
    const size_t off_recT   = off_cursor + 12032;                      // T u32
    const size_t off_recPI  = off_recT + (size_t)T * 4u;               // T u32
    const size_t need_sort  = off_recPI + (size_t)T * 4u;

    char* ws = (char*)d_ws;

    if (ws_size >= need_sort) {
        float*    tab    = (float*)ws;
        unsigned* counts = (unsigned*)(ws + off_counts);
        unsigned* cursor = (unsigned*)(ws + off_cursor);
        unsigned* recT   = (unsigned*)(ws + off_recT);
        unsigned* recPI  = (unsigned*)(ws + off_recPI);

        tt_pair_kernel<<<NPAIR, 256, 0, stream>>>(c1, c2, tab);
        tt_zero_counts<<<(NPAIR + 255) / 256, 256, 0, stream>>>(counts);
        tt_hist<<<(T + 255) / 256, 256, 0, stream>>>(x, counts, T);
        tt_scan<<<1, 1024, 0, stream>>>(counts, cursor);
        tt_scatter<<<(T + 255) / 256, 256, 0, stream>>>(x, cursor, recT, recPI, T);
        const int waves  = (T + CHUNK - 1) / CHUNK;
        const int blocks = (waves + 3) / 4;           // 4 waves per 256-thread block
        tt_embed_sorted<<<blocks, 256, 0, stream>>>(recT, recPI, c3, tab, out, T);
    } else if (ws_size >= tab_bytes) {
        float* tab = (float*)ws;
        tt_pair_kernel<<<NPAIR, 256, 0, stream>>>(c1, c2, tab);
        const int blocks = (T + 3) / 4;
        tt_embed2_kernel<<<blocks, 256, 0, stream>>>(x, c3, tab, out, T);
    } else {
        const int blocks = (T + 3) / 4;
        tt_embed_kernel<<<blocks, 256, 0, stream>>>(x, c1, c2, c3, out, T);
    }
}

// Round 2
// 324.211 us; speedup vs baseline: 1.0311x; 1.0127x over previous
//
#include <hip/hip_runtime.h>

// TT-matrix embedding: vocab 50*60*60, embed 8*8*8, rank 16.
//
// Round-2 scheme: counting-sort tokens by pair=(i1,i2), then ONE BLOCK PER PAIR-GROUP.
//   - Each wave computes its pair's t12 row (16 floats/lane across 64 lanes) directly
//     from c1/c2 in registers -- same FMA order as the old tab kernel, so absmax is
//     bit-identical -- then loops over the group's tokens (avg 43.7/pair) doing the
//     g3 contraction + store. No 12.3 MB pair table, no tab reads, one fewer launch.
//   - Records are a single u32 (t<<6)|i3; pair is implied by blockIdx.
//
// Round-1 post-mortem: dur_us includes a ~167 us fixed workspace-poison fill
// (our kernels never appear in top-5 which is all 167-176 us fillBufferAligned,
// yet round-0 total was 334 -> the fill is inside the timed region). Controllable
// budget is the ~161 us of our kernels; floor = 268 MB out-write ~ 43 us.

#define M2M3  3600u
#define M3    60u
#define NPAIR 3000
#define NPAIR_PAD 3072

// ---------------- Phase 0: zero the histogram ----------------
__global__ __launch_bounds__(256) void tt_zero(unsigned* __restrict__ counts)
{
    const int i = blockIdx.x * blockDim.x + threadIdx.x;
    if (i < NPAIR_PAD) counts[i] = 0u;
}

// ---------------- Phase 1: histogram over pairs ----------------
__global__ __launch_bounds__(256) void tt_hist(
    const int* __restrict__ x, unsigned* __restrict__ counts, int T)
{
    const int t = blockIdx.x * blockDim.x + threadIdx.x;
    if (t >= T) return;
    const unsigned id = (unsigned)x[t];
    atomicAdd(&counts[id / M3], 1u);        // pair = id/60
}

// ---------------- Phase 2: exclusive scan (1 block) ----------------
__global__ __launch_bounds__(1024) void tt_scan(
    const unsigned* __restrict__ counts, unsigned* __restrict__ cursor)
{
    __shared__ unsigned buf[1024];
    const int tid = threadIdx.x;
    const int b = tid * 3;
    unsigned c0 = 0, c1 = 0, c2 = 0;
    if (b     < NPAIR) c0 = counts[b];
    if (b + 1 < NPAIR) c1 = counts[b + 1];
    if (b + 2 < NPAIR) c2 = counts[b + 2];
    const unsigned local = c0 + c1 + c2;
    buf[tid] = local;
    __syncthreads();
    for (int off = 1; off < 1024; off <<= 1) {
        const unsigned v = (tid >= off) ? buf[tid - off] : 0u;
        __syncthreads();
        buf[tid] += v;
        __syncthreads();
    }
    const unsigned excl = buf[tid] - local;
    if (b     < NPAIR) cursor[b]     = excl;
    if (b + 1 < NPAIR) cursor[b + 1] = excl + c0;
    if (b + 2 < NPAIR) cursor[b + 2] = excl + c0 + c1;
}

// ---------------- Phase 3: scatter records ----------------
__global__ __launch_bounds__(256) void tt_scatter(
    const int* __restrict__ x, unsigned* __restrict__ cursor,
    unsigned* __restrict__ rec, int T)
{
    const int t = blockIdx.x * blockDim.x + threadIdx.x;
    if (t >= T) return;
    const unsigned id   = (unsigned)x[t];
    const unsigned pair = id / M3;
    const unsigned i3   = id - pair * M3;
    const unsigned pos  = atomicAdd(&cursor[pair], 1u);
    rec[pos] = ((unsigned)t << 6) | i3;     // t:17b | i3:6b
}

// ---------------- Phase 4: per-pair-group embed ----------------
// grid = NPAIR blocks x 256 threads (4 waves). After scatter, cursor[p] = group END;
// start = cursor[p] - counts[p]. Each wave computes the pair's t12 row in registers
// (identical FMA order to the old tab kernel), then serially processes its quarter
// of the group's tokens via readlane-broadcast records.
__global__ __launch_bounds__(256) void tt_embed_grouped(
    const unsigned* __restrict__ rec,
    const unsigned* __restrict__ counts,
    const unsigned* __restrict__ cursor,
    const float* __restrict__ c1,   // [50][8][16]
    const float* __restrict__ c2,   // [60][16][8][16]
    const float* __restrict__ c3,   // [60][16][8]
    float* __restrict__ out)        // [T][512]
{
    const int p    = blockIdx.x;            // pair = i1*60 + i2
    const int lane = threadIdx.x & 63;
    const int w    = threadIdx.x >> 6;      // wave 0..3
    const int a    = lane >> 3;
    const int b    = lane & 7;

    // group bounds -> scalar
    unsigned end = cursor[p];
    unsigned cnt = counts[p];
    end = __builtin_amdgcn_readfirstlane(end);
    cnt = __builtin_amdgcn_readfirstlane(cnt);
    const unsigned start = end - cnt;

    // this wave's contiguous share of the group
    const unsigned q = cnt >> 2, r = cnt & 3u;
    const unsigned nw = q + ((unsigned)w < r ? 1u : 0u);
    if (nw == 0) return;                    // no barriers below -> safe wave exit
    const unsigned bw = start + (unsigned)w * q + min((unsigned)w, r);

    // ---- compute t12 row for this pair, in registers ----
    // lane ab holds tf[s] = sum_r g1[a][r] * g2[r][b][s], s = 0..15
    const int i1 = p / 60;
    const int i2 = p - i1 * 60;
    const float4* __restrict__ g1v = (const float4*)(c1 + i1 * 128 + a * 16);
    const float*  __restrict__ g2  = c2 + i2 * 2048 + b * 16;

    float4 a1q[4];
#pragma unroll
    for (int k = 0; k < 4; ++k) a1q[k] = g1v[k];
    const float* a1f = (const float*)a1q;

    float4 t4[4];
#pragma unroll
    for (int k = 0; k < 4; ++k) t4[k] = make_float4(0.f, 0.f, 0.f, 0.f);
#pragma unroll
    for (int rr = 0; rr < 16; ++rr) {
        const float a1 = a1f[rr];
        const float4* row = (const float4*)(g2 + rr * 128);
#pragma unroll
        for (int k = 0; k < 4; ++k) {
            const float4 v = row[k];
            t4[k].x = fmaf(a1, v.x, t4[k].x);
            t4[k].y = fmaf(a1, v.y, t4[k].y);
            t4[k].z = fmaf(a1, v.z, t4[k].z);
            t4[k].w = fmaf(a1, v.w, t4[k].w);
        }
    }
    const float* tf = (const float*)t4;     // tf[s], s = 0..15

    // ---- token loop over this wave's share (batches of 64 records) ----
    for (unsigned off = 0; off < nw; off += 64u) {
        const unsigned m = min(64u, nw - off);      // wave-uniform
        unsigned rj = 0u;
        if ((unsigned)lane < m) rj = rec[bw + off + (unsigned)lane];

        for (unsigned j = 0; j < m; ++j) {
            const unsigned rv = __builtin_amdgcn_readlane(rj, (int)j);
            const unsigned t  = rv >> 6;
            const unsigned i3 = rv & 63u;

            const float4* __restrict__ g3 = (const float4*)(c3 + i3 * 128u);

            float o[8];
#pragma unroll
            for (int c = 0; c < 8; ++c) o[c] = 0.f;
#pragma unroll
            for (int s = 0; s < 16; ++s) {
                const float ts = tf[s];
                const float4 w0 = g3[s * 2 + 0];
                const float4 w1 = g3[s * 2 + 1];
                o[0] = fmaf(ts, w0.x, o[0]);
                o[1] = fmaf(ts, w0.y, o[1]);
                o[2] = fmaf(ts, w0.z, o[2]);
                o[3] = fmaf(ts, w0.w, o[3]);
                o[4] = fmaf(ts, w1.x, o[4]);
                o[5] = fmaf(ts, w1.y, o[5]);
                o[6] = fmaf(ts, w1.z, o[6]);
                o[7] = fmaf(ts, w1.w, o[7]);
            }

            float4* dst = (float4*)(out + (size_t)t * 512u + lane * 8);
            dst[0] = make_float4(o[0], o[1], o[2], o[3]);
            dst[1] = make_float4(o[4], o[5], o[6], o[7]);
        }
    }
}

// ---------------- Fallback A: round-1 two-phase via tab (needs 12.3 MB ws) ----------------
__global__ __launch_bounds__(256) void tt_pair_kernel(
    const float* __restrict__ c1, const float* __restrict__ c2,
    float* __restrict__ tab)
{
    const int pair = blockIdx.x;
    const int i1 = pair / 60;
    const int i2 = pair - i1 * 60;
    const int tid = threadIdx.x;
    const int qq = tid >> 6;
    const int ab = tid & 63;
    const int a  = ab >> 3;
    const int b  = ab & 7;
    const float* __restrict__ g1 = c1 + i1 * 128 + a * 16;
    const float* __restrict__ g2 = c2 + i2 * 2048 + b * 16 + qq * 4;
    float4 acc = make_float4(0.f, 0.f, 0.f, 0.f);
#pragma unroll
    for (int rr = 0; rr < 16; ++rr) {
        const float a1 = g1[rr];
        const float4 v = *(const float4*)(g2 + rr * 128);
        acc.x = fmaf(a1, v.x, acc.x);
        acc.y = fmaf(a1, v.y, acc.y);
        acc.z = fmaf(a1, v.z, acc.z);
        acc.w = fmaf(a1, v.w, acc.w);
    }
    *(float4*)(tab + (size_t)pair * 1024 + tid * 4) = acc;
}

__global__ __launch_bounds__(256) void tt_embed2_kernel(
    const int* __restrict__ x, const float* __restrict__ c3,
    const float* __restrict__ tab, float* __restrict__ out, int T)
{
    const int u    = (int)((blockIdx.x * blockDim.x + threadIdx.x) >> 6);
    const int lane = threadIdx.x & 63;
    if (u >= T) return;
    const unsigned id  = __builtin_amdgcn_readfirstlane((unsigned)x[u]);
    const unsigned i1  = id / M2M3;
    const unsigned rem = id - i1 * M2M3;
    const unsigned i2  = rem / M3;
    const unsigned i3  = rem - i2 * M3;
    const float* tp = tab + (size_t)(i1 * 60u + i2) * 1024u;
    float4 t[4];
#pragma unroll
    for (int k = 0; k < 4; ++k)
        t[k] = *(const float4*)(tp + k * 256 + lane * 4);
    const float* tf = (const float*)t;
    const float4* __restrict__ g3 = (const float4*)(c3 + i3 * 128u);
    float o[8];
#pragma unroll
    for (int c = 0; c < 8; ++c) o[c] = 0.f;
#pragma unroll
    for (int s = 0; s < 16; ++s) {
        const float ts = tf[s];
        const float4 w0 = g3[s * 2 + 0];
        const float4 w1 = g3[s * 2 + 1];
        o[0]=fmaf(ts,w0.x,o[0]); o[1]=fmaf(ts,w0.y,o[1]);
        o[2]=fmaf(ts,w0.z,o[2]); o[3]=fmaf(ts,w0.w,o[3]);
        o[4]=fmaf(ts,w1.x,o[4]); o[5]=fmaf(ts,w1.y,o[5]);
        o[6]=fmaf(ts,w1.z,o[6]); o[7]=fmaf(ts,w1.w,o[7]);
    }
    float4* dst = (float4*)(out + (size_t)u * 512 + lane * 8);
    dst[0] = make_float4(o[0], o[1], o[2], o[3]);
    dst[1] = make_float4(o[4], o[5], o[6], o[7]);
}

// ---------------- Fallback B: single-pass (tiny ws) ----------------
__global__ __launch_bounds__(256) void tt_embed_kernel(
    const int* __restrict__ x, const float* __restrict__ c1,
    const float* __restrict__ c2, const float* __restrict__ c3,
    float* __restrict__ out, int T)
{
    const int u    = (int)((blockIdx.x * blockDim.x + threadIdx.x) >> 6);
    const int lane = threadIdx.x & 63;
    if (u >= T) return;
    const int a = lane >> 3, b = lane & 7;
    const unsigned id  = (unsigned)x[u];
    const unsigned i1  = id / M2M3;
    const unsigned rem = id - i1 * M2M3;
    const unsigned i2  = rem / M3;
    const unsigned i3  = rem - i2 * M3;
    const float4* g1 = (const float4*)(c1 + i1 * 128u + a * 16);
    const float*  g2 = c2 + i2 * 2048u + b * 16;
    const float4* g3 = (const float4*)(c3 + i3 * 128u);
    float4 a1v[4];
#pragma unroll
    for (int k = 0; k < 4; ++k) a1v[k] = g1[k];
    const float* a1f = (const float*)a1v;
    float t12[16];
#pragma unroll
    for (int s = 0; s < 16; ++s) t12[s] = 0.f;
#pragma unroll
    for (int rr = 0; rr < 16; ++rr) {
        const float a1 = a1f[rr];
        const float4* row = (const float4*)(g2 + rr * 128);
#pragma unroll
        for (int k = 0; k < 4; ++k) {
            const float4 v = row[k];
            t12[k*4+0] = fmaf(a1, v.x, t12[k*4+0]);
            t12[k*4+1] = fmaf(a1, v.y, t12[k*4+1]);
            t12[k*4+2] = fmaf(a1, v.z, t12[k*4+2]);
            t12[k*4+3] = fmaf(a1, v.w, t12[k*4+3]);
        }
    }
    float o[8];
#pragma unroll
    for (int c = 0; c < 8; ++c) o[c] = 0.f;
#pragma unroll
    for (int s = 0; s < 16; ++s) {
        const float ts = t12[s];
        const float4 w0 = g3[s*2+0];
        const float4 w1 = g3[s*2+1];
        o[0]=fmaf(ts,w0.x,o[0]); o[1]=fmaf(ts,w0.y,o[1]);
        o[2]=fmaf(ts,w0.z,o[2]); o[3]=fmaf(ts,w0.w,o[3]);
        o[4]=fmaf(ts,w1.x,o[4]); o[5]=fmaf(ts,w1.y,o[5]);
        o[6]=fmaf(ts,w1.z,o[6]); o[7]=fmaf(ts,w1.w,o[7]);
    }
    float4* dst = (float4*)(out + (size_t)u * 512 + lane * 8);
    dst[0] = make_float4(o[0], o[1], o[2], o[3]);
    dst[1] = make_float4(o[4], o[5], o[6], o[7]);
}

extern "C" void kernel_launch(void* const* d_in, const int* in_sizes, int n_in,
                              void* d_out, int out_size, void* d_ws, size_t ws_size,
                              hipStream_t stream) {
    const int*   x  = (const int*)d_in[0];
    const float* c1 = (const float*)d_in[1];
    const float* c2 = (const float*)d_in[2];
    const float* c3 = (const float*)d_in[3];
    float* out = (float*)d_out;

    const int T = in_sizes[0];                        // 131072 tokens

    // sorted-path workspace: counts[3072] | cursor[3072] | rec[T]  (~550 KB)
    const size_t off_counts = 0;
    const size_t off_cursor = off_counts + (size_t)NPAIR_PAD * 4u;
    const size_t off_rec    = off_cursor + (size_t)NPAIR_PAD * 4u;
    const size_t need_sort  = off_rec + (size_t)T * 4u;
    const size_t tab_bytes  = (size_t)NPAIR * 1024u * sizeof(float);

    char* ws = (char*)d_ws;

    if (ws_size >= need_sort) {
        unsigned* counts = (unsigned*)(ws + off_counts);
        unsigned* cursor = (unsigned*)(ws + off_cursor);
        unsigned* rec    = (unsigned*)(ws + off_rec);

        tt_zero<<<(NPAIR_PAD + 255) / 256, 256, 0, stream>>>(counts);
        tt_hist<<<(T + 255) / 256, 256, 0, stream>>>(x, counts, T);
        tt_scan<<<1, 1024, 0, stream>>>(counts, cursor);
        tt_scatter<<<(T + 255) / 256, 256, 0, stream>>>(x, cursor, rec, T);
        tt_embed_grouped<<<NPAIR, 256, 0, stream>>>(rec, counts, cursor,
                                                    c1, c2, c3, out);
    } else if (ws_size >= tab_bytes) {
        float* tab = (float*)ws;
        tt_pair_kernel<<<NPAIR, 256, 0, stream>>>(c1, c2, tab);
        const int blocks = (T + 3) / 4;
        tt_embed2_kernel<<<blocks, 256, 0, stream>>>(x, c3, tab, out, T);
    } else {
        const int blocks = (T + 3) / 4;
        tt_embed_kernel<<<blocks, 256, 0, stream>>>(x, c1, c2, c3, out, T);
    }
}